// Round 3
// baseline (2875.092 us; speedup 1.0000x reference)
//
#include <hip/hip_runtime.h>
#include <math.h>

#define B_   16
#define N_   2048
#define K_   20
#define C_   64
#define OUT_ 64
#define NEG_SLOPE 0.2f
#define NTILE 8

// ---------------------------------------------------------------------------
// Kernel 1: KNN. One block per (b, n). Distances computed in DOUBLE precision
// (true ordering; matches an fp64 numpy reference's top_k exactly).
// pd[m] = 2*<p_n,p_m> - |p_n|^2 - |p_m|^2 ; top-(K+1), tie-break lower index,
// drop the first hit (self, pd=0 max since all others < 0).
// ---------------------------------------------------------------------------
__global__ __launch_bounds__(256)
void knn_kernel(const float* __restrict__ pos, int* __restrict__ idx_out) {
    __shared__ double pds[N_];
    __shared__ unsigned long long redk[4];
    __shared__ int redi[4];
    const int t = threadIdx.x;
    const int b = blockIdx.x / N_;
    const int n = blockIdx.x % N_;
    const float* pb = pos + (size_t)b * 3 * N_;

    const double qx = (double)pb[n];
    const double qy = (double)pb[N_ + n];
    const double qz = (double)pb[2 * N_ + n];
    const double xxn = qx * qx + qy * qy + qz * qz;

    for (int m = t; m < N_; m += 256) {
        double px = (double)pb[m];
        double py = (double)pb[N_ + m];
        double pz = (double)pb[2 * N_ + m];
        double inner = qx * px + qy * py + qz * pz;
        double xxm   = px * px + py * py + pz * pz;
        pds[m] = 2.0 * inner - xxn - xxm;
    }
    __syncthreads();

    int* myidx = idx_out + (size_t)blockIdx.x * K_;
    for (int it = 0; it < K_ + 1; ++it) {
        unsigned long long bk = 0ull;
        int bi = 0x7FFFFFFF;
        for (int m = t; m < N_; m += 256) {
            unsigned long long u =
                (unsigned long long)__double_as_longlong(pds[m]);
            u = (u >> 63) ? ~u : (u | 0x8000000000000000ull);
            if (u > bk || (u == bk && m < bi)) { bk = u; bi = m; }
        }
#pragma unroll
        for (int off = 32; off > 0; off >>= 1) {
            unsigned long long ok = __shfl_down(bk, (unsigned)off, 64);
            int oi = __shfl_down(bi, (unsigned)off, 64);
            if (ok > bk || (ok == bk && oi < bi)) { bk = ok; bi = oi; }
        }
        if ((t & 63) == 0) { redk[t >> 6] = bk; redi[t >> 6] = bi; }
        __syncthreads();
        if (t == 0) {
            unsigned long long bb = redk[0]; int ii = redi[0];
#pragma unroll
            for (int w = 1; w < 4; ++w) {
                if (redk[w] > bb || (redk[w] == bb && redi[w] < ii)) {
                    bb = redk[w]; ii = redi[w];
                }
            }
            pds[ii] = -INFINITY;
            if (it > 0) myidx[it - 1] = ii;
        }
        __syncthreads();
    }
}

// ---------------------------------------------------------------------------
// Kernel 2: bx[b,o,n] = sum_c basis_W[o,c] * x[b,c,n]  (fp32 out to ws)
// ---------------------------------------------------------------------------
__global__ __launch_bounds__(256)
void bx_kernel(const float* __restrict__ x, const float* __restrict__ W,
               float* __restrict__ bxw) {
    const int n = blockIdx.x * 256 + threadIdx.x;
    const int o = blockIdx.y;
    const int b = blockIdx.z;
    const float* xb = x + (size_t)b * C_ * N_;
    float acc = 0.f;
#pragma unroll
    for (int c = 0; c < C_; ++c)
        acc = fmaf(W[o * C_ + c], xb[c * N_ + n], acc);
    bxw[((size_t)b * C_ + o) * N_ + n] = acc;
}

// ---------------------------------------------------------------------------
// Kernel 3: fused per-point pipeline. One block handles NTILE consecutive n
// of one batch. Weights staged to LDS once per block with odd strides
// (bank-conflict padding). Activations in LDS laid out [channel][k].
// ---------------------------------------------------------------------------
// padded strides
#define SDK1 9     // 16 x 8  -> stride 9
#define SDK2 17    // 32 x 16 -> stride 17
#define SFF1 65    // 32 x 64 -> stride 65
#define SFF2 33    // 64 x 32 -> stride 33
#define SEDG 129   // 64 x 128-> stride 129

__device__ __forceinline__ void stage_pad(const float* __restrict__ s, float* d,
                                          int rows, int cols, int stride, int t) {
    for (int i = t; i < rows * cols; i += 256) {
        int r = i / cols, c = i - r * cols;
        d[r * stride + c] = s[i];
    }
}
__device__ __forceinline__ void stage_vec(const float* __restrict__ s, float* d,
                                          int cnt, int t) {
    for (int i = t; i < cnt; i += 256) d[i] = s[i];
}

__global__ __launch_bounds__(256)
void fused_kernel(const float* __restrict__ x, const float* __restrict__ glf,
                  const float* __restrict__ appf,
                  const float* __restrict__ dk_W1, const float* __restrict__ dk_b1,
                  const float* __restrict__ dk_g1, const float* __restrict__ dk_be1,
                  const float* __restrict__ dk_W2, const float* __restrict__ dk_b2,
                  const float* __restrict__ act_g, const float* __restrict__ act_b,
                  const float* __restrict__ ff_W1, const float* __restrict__ ff_g1,
                  const float* __restrict__ ff_be1, const float* __restrict__ ff_W2,
                  const float* __restrict__ edge_W, const float* __restrict__ edge_g,
                  const float* __restrict__ edge_be,
                  const float* __restrict__ bxw, const int* __restrict__ idx_ws,
                  float* __restrict__ out) {
    __shared__ float w_dk1[16 * SDK1], bdk1[16], gdk1[16], bedk1[16];
    __shared__ float w_dk2[32 * SDK2], bdk2[32];
    __shared__ float w_ff1[32 * SFF1], gff1[32], beff1[32];
    __shared__ float w_ff2[64 * SFF2];
    __shared__ float gact[64], bact[64];
    __shared__ float w_edge[64 * SEDG], gedge[64], beedge[64];
    __shared__ float xcol[64], base_s[64];
    __shared__ float appf_s[K_ * 8];   // [k][j]
    __shared__ float h_s[16 * K_];     // [o][k]
    __shared__ float rif_s[64 * K_];   // [c][k]  (upper 32 ch = glf; later feat-x)
    __shared__ float t_s[32 * K_];     // [o][k]
    __shared__ int   idx_s[K_];
    __shared__ float omax[256];

    const int t = threadIdx.x;
    const int b  = blockIdx.x / (N_ / NTILE);
    const int n0 = (blockIdx.x % (N_ / NTILE)) * NTILE;

    // ---- stage all weights once per block ----
    stage_pad(dk_W1, w_dk1, 16, 8, SDK1, t);
    stage_vec(dk_b1, bdk1, 16, t);
    stage_vec(dk_g1, gdk1, 16, t);
    stage_vec(dk_be1, bedk1, 16, t);
    stage_pad(dk_W2, w_dk2, 32, 16, SDK2, t);
    stage_vec(dk_b2, bdk2, 32, t);
    stage_pad(ff_W1, w_ff1, 32, 64, SFF1, t);
    stage_vec(ff_g1, gff1, 32, t);
    stage_vec(ff_be1, beff1, 32, t);
    stage_pad(ff_W2, w_ff2, 64, 32, SFF2, t);
    stage_vec(act_g, gact, 64, t);
    stage_vec(act_b, bact, 64, t);
    stage_pad(edge_W, w_edge, 64, 128, SEDG, t);
    stage_vec(edge_g, gedge, 64, t);
    stage_vec(edge_be, beedge, 64, t);
    __syncthreads();

    for (int nn = n0; nn < n0 + NTILE; ++nn) {
        // ---- load per-n activations ----
        if (t < 64) xcol[t] = x[((size_t)b * C_ + t) * N_ + nn];
        if (t < K_) idx_s[t] = idx_ws[((size_t)b * N_ + nn) * K_ + t];
        if (t >= 64 && t < 64 + K_ * 8) {
            int e = t - 64;
            appf_s[e] = appf[((size_t)b * N_ + nn) * K_ * 8 + e];
        }
        for (int e = t; e < 32 * K_; e += 256) {
            int c2 = e / K_, k = e - c2 * K_;
            rif_s[(32 + c2) * K_ + k] =
                glf[(((size_t)b * 32 + c2) * N_ + nn) * K_ + k];
        }
        __syncthreads();

        // ---- base_o = edge_W[o, 64:128] . x  (k-independent) ----
        if (t < 64) {
            float acc = 0.f;
#pragma unroll
            for (int c = 0; c < 64; ++c)
                acc = fmaf(w_edge[t * SEDG + 64 + c], xcol[c], acc);
            base_s[t] = acc;
        }
        // ---- h = relu(bn(dk_W1 @ appf + b1)) : 16 x K ----
        for (int e = t; e < 16 * K_; e += 256) {
            int o = e / K_, k = e - o * K_;
            float acc = bdk1[o];
#pragma unroll
            for (int j = 0; j < 8; ++j)
                acc = fmaf(w_dk1[o * SDK1 + j], appf_s[k * 8 + j], acc);
            float v = acc * gdk1[o] + bedk1[o];
            h_s[o * K_ + k] = fmaxf(v, 0.f);
        }
        __syncthreads();

        // ---- rif[0:32] = dk_W2 @ h + b2 : 32 x K ----
        for (int e = t; e < 32 * K_; e += 256) {
            int o = e / K_, k = e - o * K_;
            float acc = bdk2[o];
#pragma unroll
            for (int j = 0; j < 16; ++j)
                acc = fmaf(w_dk2[o * SDK2 + j], h_s[j * K_ + k], acc);
            rif_s[o * K_ + k] = acc;
        }
        __syncthreads();

        // ---- t = leaky(bn(ff_W1 @ rif)) : 32 x K ----
        for (int e = t; e < 32 * K_; e += 256) {
            int o = e / K_, k = e - o * K_;
            float acc = 0.f;
#pragma unroll
            for (int c = 0; c < 64; ++c)
                acc = fmaf(w_ff1[o * SFF1 + c], rif_s[c * K_ + k], acc);
            float v = acc * gff1[o] + beff1[o];
            t_s[o * K_ + k] = (v >= 0.f) ? v : NEG_SLOPE * v;
        }
        __syncthreads();

        // ---- att = sigmoid(ff_W2 @ t); rif *= att : 64 x K ----
        for (int e = t; e < 64 * K_; e += 256) {
            int o = e / K_, k = e - o * K_;
            float acc = 0.f;
#pragma unroll
            for (int j = 0; j < 32; ++j)
                acc = fmaf(w_ff2[o * SFF2 + j], t_s[j * K_ + k], acc);
            float a = 1.f / (1.f + expf(-acc));
            rif_s[o * K_ + k] *= a;
        }
        __syncthreads();

        // ---- feat = relu(bn(rif * gather(bx))); store (feat - x) ----
        for (int e = t; e < 64 * K_; e += 256) {
            int c = e / K_, k = e - c * K_;
            float g = bxw[((size_t)b * C_ + c) * N_ + idx_s[k]];
            float v = rif_s[c * K_ + k] * g;
            v = v * gact[c] + bact[c];
            v = fmaxf(v, 0.f);
            rif_s[c * K_ + k] = v - xcol[c];
        }
        __syncthreads();

        // ---- edge conv + leaky + max over k ----
        {
            int o = t >> 2, kg = t & 3;
            float mx = -INFINITY;
#pragma unroll
            for (int i = 0; i < 5; ++i) {
                int k = kg * 5 + i;
                float acc = base_s[o];
#pragma unroll
                for (int c = 0; c < 64; ++c)
                    acc = fmaf(w_edge[o * SEDG + c], rif_s[c * K_ + k], acc);
                float v = acc * gedge[o] + beedge[o];
                v = (v >= 0.f) ? v : NEG_SLOPE * v;
                mx = fmaxf(mx, v);
            }
            omax[t] = mx;
        }
        __syncthreads();
        if (t < 64) {
            float m0 = fmaxf(fmaxf(omax[t * 4], omax[t * 4 + 1]),
                             fmaxf(omax[t * 4 + 2], omax[t * 4 + 3]));
            out[((size_t)b * OUT_ + t) * N_ + nn] = m0;
        }
        __syncthreads();
    }
}

// ---------------------------------------------------------------------------
extern "C" void kernel_launch(void* const* d_in, const int* in_sizes, int n_in,
                              void* d_out, int out_size, void* d_ws, size_t ws_size,
                              hipStream_t stream) {
    (void)in_sizes; (void)n_in; (void)out_size; (void)ws_size;
    const float* pos     = (const float*)d_in[0];
    const float* x       = (const float*)d_in[1];
    const float* glf     = (const float*)d_in[2];
    const float* appf    = (const float*)d_in[3];
    const float* basis_W = (const float*)d_in[4];
    const float* dk_W1   = (const float*)d_in[5];
    const float* dk_b1   = (const float*)d_in[6];
    const float* dk_g1   = (const float*)d_in[7];
    const float* dk_be1  = (const float*)d_in[8];
    const float* dk_W2   = (const float*)d_in[9];
    const float* dk_b2   = (const float*)d_in[10];
    const float* act_g   = (const float*)d_in[11];
    const float* act_b   = (const float*)d_in[12];
    const float* ff_W1   = (const float*)d_in[13];
    const float* ff_g1   = (const float*)d_in[14];
    const float* ff_be1  = (const float*)d_in[15];
    const float* ff_W2   = (const float*)d_in[16];
    const float* edge_W  = (const float*)d_in[17];
    const float* edge_g  = (const float*)d_in[18];
    const float* edge_be = (const float*)d_in[19];
    float* out = (float*)d_out;

    int*   idx_ws = (int*)d_ws;
    float* bxw    = (float*)((char*)d_ws + (size_t)B_ * N_ * K_ * sizeof(int));

    hipLaunchKernelGGL(knn_kernel, dim3(B_ * N_), dim3(256), 0, stream,
                       pos, idx_ws);
    hipLaunchKernelGGL(bx_kernel, dim3(N_ / 256, C_, B_), dim3(256), 0, stream,
                       x, basis_W, bxw);
    hipLaunchKernelGGL(fused_kernel, dim3(B_ * (N_ / NTILE)), dim3(256), 0, stream,
                       x, glf, appf, dk_W1, dk_b1, dk_g1, dk_be1, dk_W2, dk_b2,
                       act_g, act_b, ff_W1, ff_g1, ff_be1, ff_W2,
                       edge_W, edge_g, edge_be, bxw, idx_ws, out);
}

// Round 4
// 1899.118 us; speedup vs baseline: 1.5139x; 1.5139x over previous
//
#include <hip/hip_runtime.h>
#include <math.h>

#define B_   16
#define N_   2048
#define K_   20
#define C_   64
#define OUT_ 64
#define NEG_SLOPE 0.2f

// ---------------------------------------------------------------------------
// Kernel 1: KNN — one wave per point. 32 fp64 distances per lane in registers,
// 21 rounds of (masked in-lane argmax -> 6-step butterfly reduce).
// Tie-break: value desc, lowest index (lane chunks are contiguous so lane
// order == index order). Round 0 result (self / duplicate) is dropped.
// ---------------------------------------------------------------------------
__global__ __launch_bounds__(256)
void knn_kernel(const float* __restrict__ pos, int* __restrict__ idx_out) {
    const int t = threadIdx.x;
    const int wv = t >> 6, l = t & 63;
    const int gid = blockIdx.x * 4 + wv;
    const int b = gid / N_, n = gid % N_;
    const float* pb = pos + (size_t)b * 3 * N_;

    const double qx = (double)pb[n];
    const double qy = (double)pb[N_ + n];
    const double qz = (double)pb[2 * N_ + n];
    const double xxn = qx * qx + qy * qy + qz * qz;

    double d[32];
    const int m0 = l * 32;
#pragma unroll
    for (int j4 = 0; j4 < 8; ++j4) {
        float4 px = *(const float4*)(pb + m0 + 4 * j4);
        float4 py = *(const float4*)(pb + N_ + m0 + 4 * j4);
        float4 pz = *(const float4*)(pb + 2 * N_ + m0 + 4 * j4);
#define DCOMP(JJ, PX, PY, PZ)                                            \
        {   double ddx = (double)(PX), ddy = (double)(PY), ddz = (double)(PZ); \
            double inner = qx * ddx + qy * ddy + qz * ddz;               \
            double xxm   = ddx * ddx + ddy * ddy + ddz * ddz;            \
            d[4 * j4 + JJ] = 2.0 * inner - xxn - xxm; }
        DCOMP(0, px.x, py.x, pz.x)
        DCOMP(1, px.y, py.y, pz.y)
        DCOMP(2, px.z, py.z, pz.z)
        DCOMP(3, px.w, py.w, pz.w)
#undef DCOMP
    }

    unsigned sel = 0u;
    for (int r = 0; r < K_ + 1; ++r) {
        double bk = -INFINITY;
        int bi = 0x7FFFFFFF;
#pragma unroll
        for (int j = 0; j < 32; ++j) {
            bool live = ((sel >> j) & 1u) == 0u;
            if (live && d[j] > bk) { bk = d[j]; bi = m0 + j; }
        }
#pragma unroll
        for (int off = 1; off < 64; off <<= 1) {
            double ok = __shfl_xor(bk, off, 64);
            int    oi = __shfl_xor(bi, off, 64);
            if (ok > bk || (ok == bk && oi < bi)) { bk = ok; bi = oi; }
        }
        if ((bi >> 5) == l) sel |= 1u << (bi & 31);
        if (l == 0 && r > 0) idx_out[(size_t)gid * K_ + (r - 1)] = bi;
    }
}

// ---------------------------------------------------------------------------
// Kernel 2: bx[b,o,n] = sum_c basis_W[o,c] * x[b,c,n]  (fp32 out to ws)
// ---------------------------------------------------------------------------
__global__ __launch_bounds__(256)
void bx_kernel(const float* __restrict__ x, const float* __restrict__ W,
               float* __restrict__ bxw) {
    const int n = blockIdx.x * 256 + threadIdx.x;
    const int o = blockIdx.y;
    const int b = blockIdx.z;
    const float* xb = x + (size_t)b * C_ * N_;
    float acc = 0.f;
#pragma unroll
    for (int c = 0; c < C_; ++c)
        acc = fmaf(W[o * C_ + c], xb[c * N_ + n], acc);
    bxw[((size_t)b * C_ + o) * N_ + n] = acc;
}

// ---------------------------------------------------------------------------
// Kernel 3: fused pipeline — ONE WAVE PER POINT, zero __syncthreads.
// 4 waves/block, each wave processes NPW consecutive n. Per-wave 8 KB LDS
// slice: RIF[20][64] (k-major: 64-wide dot reads are same-address broadcast),
// SCR (appf[20][8] + h[20][16], later t[20][32]), XCOL[64], IDX[20].
// Weights read from global (L1/L2-resident), row chunks held in registers
// across the 20-k loop. Within-wave LDS write->read needs no barrier
// (DS ops are in-order per wave; lanes are lockstep).
// ---------------------------------------------------------------------------
#define WPB 4
#define NPW 4
#define NBLK (WPB * NPW)   // 16 n per block
#define SLICE 2048         // floats per wave slice (8 KB)

__global__ __launch_bounds__(256, 4)
void fused_kernel(const float* __restrict__ x, const float* __restrict__ glf,
                  const float* __restrict__ appf,
                  const float* __restrict__ dk_W1, const float* __restrict__ dk_b1,
                  const float* __restrict__ dk_g1, const float* __restrict__ dk_be1,
                  const float* __restrict__ dk_W2, const float* __restrict__ dk_b2,
                  const float* __restrict__ act_g, const float* __restrict__ act_b,
                  const float* __restrict__ ff_W1, const float* __restrict__ ff_g1,
                  const float* __restrict__ ff_be1, const float* __restrict__ ff_W2,
                  const float* __restrict__ edge_W, const float* __restrict__ edge_g,
                  const float* __restrict__ edge_be,
                  const float* __restrict__ bxw, const int* __restrict__ idx_ws,
                  float* __restrict__ out) {
    __shared__ float lds[WPB * SLICE];
    const int t = threadIdx.x, wv = t >> 6, l = t & 63;
    float* Wb   = lds + wv * SLICE;
    float* RIF  = Wb;            // [20][64]
    float* SCR  = Wb + 1280;     // appf [20][8] @0 ; h [20][16] @160 ; t [20][32] @0
    float* XCOL = Wb + 1920;     // 64
    int*   IDX  = (int*)(Wb + 1984); // 20

    const int b    = blockIdx.x / (N_ / NBLK);
    const int nblk = (blockIdx.x % (N_ / NBLK)) * NBLK;
    const int nw0  = nblk + wv * NPW;

    // ---- hoisted per-lane constants (n-invariant) ----
    const int o16 = l >> 2, o32 = l >> 1;
    const int kq5 = (l & 3) * 5, kh10 = (l & 1) * 10;
    const float bdk1h = dk_b1[o16], gdk1h = dk_g1[o16], bedk1h = dk_be1[o16];
    const float bdk2h = dk_b2[o32];
    const float gff1h = ff_g1[o32], beff1h = ff_be1[o32];
    const float gacth = act_g[l],  bacth = act_b[l];
    const float gedgh = edge_g[l], beedgh = edge_be[l];
    const float4 wd1a = *(const float4*)(dk_W1 + o16 * 8);
    const float4 wd1b = *(const float4*)(dk_W1 + o16 * 8 + 4);
    const float4 wd20 = *(const float4*)(dk_W2 + o32 * 16);
    const float4 wd21 = *(const float4*)(dk_W2 + o32 * 16 + 4);
    const float4 wd22 = *(const float4*)(dk_W2 + o32 * 16 + 8);
    const float4 wd23 = *(const float4*)(dk_W2 + o32 * 16 + 12);
    const float* wF1  = ff_W1 + o32 * 64;
    const float* wF2  = ff_W2 + l * 32;
    const float* wEd  = edge_W + l * 128;
    const float* xrow  = x   + ((size_t)b * C_ + l) * N_;
    const float* bxrow = bxw + ((size_t)b * C_ + l) * N_;

#pragma unroll 1
    for (int i = 0; i < NPW; ++i) {
        const int n = nw0 + i;

        // ---- per-n loads ----
        const float xc = xrow[n];
        XCOL[l] = xc;
        if (l < K_) IDX[l] = idx_ws[((size_t)b * N_ + n) * K_ + l];
        if (l >= 32) {                 // appf: 160 contiguous floats
            const int l2 = l - 32;
            const float4* src = (const float4*)(appf + ((size_t)b * N_ + n) * (K_ * 8));
            *(float4*)(SCR + 4 * l2) = src[l2];
            if (l2 < 8) *(float4*)(SCR + 128 + 4 * l2) = src[32 + l2];
        } else {                       // glf row c2=l -> RIF[k][32+l]
            const float* g = glf + (((size_t)b * 32 + l) * N_ + n) * K_;
#pragma unroll
            for (int kc = 0; kc < 5; ++kc) {
                float4 v = *(const float4*)(g + 4 * kc);
                RIF[(4 * kc + 0) * 64 + 32 + l] = v.x;
                RIF[(4 * kc + 1) * 64 + 32 + l] = v.y;
                RIF[(4 * kc + 2) * 64 + 32 + l] = v.z;
                RIF[(4 * kc + 3) * 64 + 32 + l] = v.w;
            }
        }

        // ---- base_l = edge_W[l, 64:128] . x ----
        float base = 0.f;
#pragma unroll
        for (int c = 0; c < 16; ++c) {
            float4 w4 = *(const float4*)(wEd + 64 + 4 * c);
            float4 x4 = *(const float4*)(XCOL + 4 * c);
            base = fmaf(w4.x, x4.x, base); base = fmaf(w4.y, x4.y, base);
            base = fmaf(w4.z, x4.z, base); base = fmaf(w4.w, x4.w, base);
        }

        // ---- h = relu(bn(dk_W1 @ appf + b1)) : lane -> o=l>>2, k=kq5+q ----
#pragma unroll
        for (int q = 0; q < 5; ++q) {
            const int k = kq5 + q;
            float4 a0 = *(const float4*)(SCR + k * 8);
            float4 a1 = *(const float4*)(SCR + k * 8 + 4);
            float acc = bdk1h;
            acc = fmaf(wd1a.x, a0.x, acc); acc = fmaf(wd1a.y, a0.y, acc);
            acc = fmaf(wd1a.z, a0.z, acc); acc = fmaf(wd1a.w, a0.w, acc);
            acc = fmaf(wd1b.x, a1.x, acc); acc = fmaf(wd1b.y, a1.y, acc);
            acc = fmaf(wd1b.z, a1.z, acc); acc = fmaf(wd1b.w, a1.w, acc);
            float v = acc * gdk1h + bedk1h;
            SCR[160 + k * 16 + o16] = fmaxf(v, 0.f);
        }

        // ---- rif[0:32] = dk_W2 @ h + b2 : lane -> o=l>>1, k=kh10+q ----
#pragma unroll
        for (int q = 0; q < 10; ++q) {
            const int k = kh10 + q;
            const float* hr = SCR + 160 + k * 16;
            float4 h0 = *(const float4*)(hr);
            float4 h1 = *(const float4*)(hr + 4);
            float4 h2 = *(const float4*)(hr + 8);
            float4 h3 = *(const float4*)(hr + 12);
            float acc = bdk2h;
            acc = fmaf(wd20.x, h0.x, acc); acc = fmaf(wd20.y, h0.y, acc);
            acc = fmaf(wd20.z, h0.z, acc); acc = fmaf(wd20.w, h0.w, acc);
            acc = fmaf(wd21.x, h1.x, acc); acc = fmaf(wd21.y, h1.y, acc);
            acc = fmaf(wd21.z, h1.z, acc); acc = fmaf(wd21.w, h1.w, acc);
            acc = fmaf(wd22.x, h2.x, acc); acc = fmaf(wd22.y, h2.y, acc);
            acc = fmaf(wd22.z, h2.z, acc); acc = fmaf(wd22.w, h2.w, acc);
            acc = fmaf(wd23.x, h3.x, acc); acc = fmaf(wd23.y, h3.y, acc);
            acc = fmaf(wd23.z, h3.z, acc); acc = fmaf(wd23.w, h3.w, acc);
            RIF[k * 64 + o32] = acc;
        }

        // ---- t = leaky(bn(ff_W1 @ rif)) : lane -> o=l>>1, k=kh10+q ----
        {
            float acc[10];
#pragma unroll
            for (int q = 0; q < 10; ++q) acc[q] = 0.f;
#pragma unroll
            for (int c = 0; c < 16; ++c) {
                float4 w4 = *(const float4*)(wF1 + 4 * c);
#pragma unroll
                for (int q = 0; q < 10; ++q) {
                    float4 r4 = *(const float4*)(RIF + (kh10 + q) * 64 + 4 * c);
                    acc[q] = fmaf(w4.x, r4.x, acc[q]);
                    acc[q] = fmaf(w4.y, r4.y, acc[q]);
                    acc[q] = fmaf(w4.z, r4.z, acc[q]);
                    acc[q] = fmaf(w4.w, r4.w, acc[q]);
                }
            }
#pragma unroll
            for (int q = 0; q < 10; ++q) {
                float v = acc[q] * gff1h + beff1h;
                v = (v >= 0.f) ? v : NEG_SLOPE * v;
                SCR[(kh10 + q) * 32 + o32] = v;   // t overwrites appf/h (dead)
            }
        }

        // ---- att = sigmoid(ff_W2 @ t); feat = relu(bn(rif*att*gather)) - x ----
        float acc2[20];
#pragma unroll
        for (int k = 0; k < 20; ++k) acc2[k] = 0.f;
#pragma unroll
        for (int c = 0; c < 8; ++c) {
            float4 w4 = *(const float4*)(wF2 + 4 * c);
#pragma unroll
            for (int k = 0; k < 20; ++k) {
                float4 t4 = *(const float4*)(SCR + k * 32 + 4 * c);
                acc2[k] = fmaf(w4.x, t4.x, acc2[k]);
                acc2[k] = fmaf(w4.y, t4.y, acc2[k]);
                acc2[k] = fmaf(w4.z, t4.z, acc2[k]);
                acc2[k] = fmaf(w4.w, t4.w, acc2[k]);
            }
        }
#pragma unroll
        for (int k = 0; k < 20; ++k) {
            float a = 1.f / (1.f + expf(-acc2[k]));
            int kidx = IDX[k];
            float gth = bxrow[kidx];
            float v = RIF[k * 64 + l] * a * gth;
            v = v * gacth + bacth;
            v = fmaxf(v, 0.f) - xc;
            RIF[k * 64 + l] = v;
        }

        // ---- edge conv + bn + leaky + max over k ----
#pragma unroll
        for (int k = 0; k < 20; ++k) acc2[k] = base;
#pragma unroll
        for (int c = 0; c < 16; ++c) {
            float4 w4 = *(const float4*)(wEd + 4 * c);
#pragma unroll
            for (int k = 0; k < 20; ++k) {
                float4 r4 = *(const float4*)(RIF + k * 64 + 4 * c);
                acc2[k] = fmaf(w4.x, r4.x, acc2[k]);
                acc2[k] = fmaf(w4.y, r4.y, acc2[k]);
                acc2[k] = fmaf(w4.z, r4.z, acc2[k]);
                acc2[k] = fmaf(w4.w, r4.w, acc2[k]);
            }
        }
        float mx = -INFINITY;
#pragma unroll
        for (int k = 0; k < 20; ++k) {
            float v = acc2[k] * gedgh + beedgh;
            v = (v >= 0.f) ? v : NEG_SLOPE * v;
            mx = fmaxf(mx, v);
        }
        out[((size_t)b * OUT_ + l) * N_ + n] = mx;
    }
}

// ---------------------------------------------------------------------------
extern "C" void kernel_launch(void* const* d_in, const int* in_sizes, int n_in,
                              void* d_out, int out_size, void* d_ws, size_t ws_size,
                              hipStream_t stream) {
    (void)in_sizes; (void)n_in; (void)out_size; (void)ws_size;
    const float* pos     = (const float*)d_in[0];
    const float* x       = (const float*)d_in[1];
    const float* glf     = (const float*)d_in[2];
    const float* appf    = (const float*)d_in[3];
    const float* basis_W = (const float*)d_in[4];
    const float* dk_W1   = (const float*)d_in[5];
    const float* dk_b1   = (const float*)d_in[6];
    const float* dk_g1   = (const float*)d_in[7];
    const float* dk_be1  = (const float*)d_in[8];
    const float* dk_W2   = (const float*)d_in[9];
    const float* dk_b2   = (const float*)d_in[10];
    const float* act_g   = (const float*)d_in[11];
    const float* act_b   = (const float*)d_in[12];
    const float* ff_W1   = (const float*)d_in[13];
    const float* ff_g1   = (const float*)d_in[14];
    const float* ff_be1  = (const float*)d_in[15];
    const float* ff_W2   = (const float*)d_in[16];
    const float* edge_W  = (const float*)d_in[17];
    const float* edge_g  = (const float*)d_in[18];
    const float* edge_be = (const float*)d_in[19];
    float* out = (float*)d_out;

    int*   idx_ws = (int*)d_ws;
    float* bxw    = (float*)((char*)d_ws + (size_t)B_ * N_ * K_ * sizeof(int));

    hipLaunchKernelGGL(knn_kernel, dim3(B_ * N_ / 4), dim3(256), 0, stream,
                       pos, idx_ws);
    hipLaunchKernelGGL(bx_kernel, dim3(N_ / 256, C_, B_), dim3(256), 0, stream,
                       x, basis_W, bxw);
    hipLaunchKernelGGL(fused_kernel, dim3(B_ * (N_ / NBLK)), dim3(256), 0, stream,
                       x, glf, appf, dk_W1, dk_b1, dk_g1, dk_be1, dk_W2, dk_b2,
                       act_g, act_b, ff_W1, ff_g1, ff_be1, ff_W2,
                       edge_W, edge_g, edge_be, bxw, idx_ws, out);
}

// Round 5
// 1696.327 us; speedup vs baseline: 1.6949x; 1.1195x over previous
//
#include <hip/hip_runtime.h>
#include <math.h>

#define B_   16
#define N_   2048
#define K_   20
#define C_   64
#define OUT_ 64
#define NEG_SLOPE 0.2f

// ---------------------------------------------------------------------------
// Kernel 1: KNN — one wave per point (unchanged from R4; bit-identical).
// ---------------------------------------------------------------------------
__global__ __launch_bounds__(256)
void knn_kernel(const float* __restrict__ pos, int* __restrict__ idx_out) {
    const int t = threadIdx.x;
    const int wv = t >> 6, l = t & 63;
    const int gid = blockIdx.x * 4 + wv;
    const int b = gid / N_, n = gid % N_;
    const float* pb = pos + (size_t)b * 3 * N_;

    const double qx = (double)pb[n];
    const double qy = (double)pb[N_ + n];
    const double qz = (double)pb[2 * N_ + n];
    const double xxn = qx * qx + qy * qy + qz * qz;

    double d[32];
    const int m0 = l * 32;
#pragma unroll
    for (int j4 = 0; j4 < 8; ++j4) {
        float4 px = *(const float4*)(pb + m0 + 4 * j4);
        float4 py = *(const float4*)(pb + N_ + m0 + 4 * j4);
        float4 pz = *(const float4*)(pb + 2 * N_ + m0 + 4 * j4);
#define DCOMP(JJ, PX, PY, PZ)                                            \
        {   double ddx = (double)(PX), ddy = (double)(PY), ddz = (double)(PZ); \
            double inner = qx * ddx + qy * ddy + qz * ddz;               \
            double xxm   = ddx * ddx + ddy * ddy + ddz * ddz;            \
            d[4 * j4 + JJ] = 2.0 * inner - xxn - xxm; }
        DCOMP(0, px.x, py.x, pz.x)
        DCOMP(1, px.y, py.y, pz.y)
        DCOMP(2, px.z, py.z, pz.z)
        DCOMP(3, px.w, py.w, pz.w)
#undef DCOMP
    }

    unsigned sel = 0u;
    for (int r = 0; r < K_ + 1; ++r) {
        double bk = -INFINITY;
        int bi = 0x7FFFFFFF;
#pragma unroll
        for (int j = 0; j < 32; ++j) {
            bool live = ((sel >> j) & 1u) == 0u;
            if (live && d[j] > bk) { bk = d[j]; bi = m0 + j; }
        }
#pragma unroll
        for (int off = 1; off < 64; off <<= 1) {
            double ok = __shfl_xor(bk, off, 64);
            int    oi = __shfl_xor(bi, off, 64);
            if (ok > bk || (ok == bk && oi < bi)) { bk = ok; bi = oi; }
        }
        if ((bi >> 5) == l) sel |= 1u << (bi & 31);
        if (l == 0 && r > 0) idx_out[(size_t)gid * K_ + (r - 1)] = bi;
    }
}

// ---------------------------------------------------------------------------
// Kernel 2: bxT[b][n][o] = sum_c basis_W[o,c] * x[b,c,n]   (TRANSPOSED out)
// Block: 256 thr = 64 o x 4 j-sub, covers 32 n. W staged to LDS (stride 65),
// x tile staged [c][n] (stride 33). Writes coalesced 256 B rows.
// ---------------------------------------------------------------------------
__global__ __launch_bounds__(256)
void bx_kernel_t(const float* __restrict__ x, const float* __restrict__ W,
                 float* __restrict__ bxT) {
    __shared__ float wS[64 * 65];
    __shared__ float xS[64 * 33];
    const int t = threadIdx.x;
    const int b = blockIdx.y;
    const int n0 = blockIdx.x * 32;

    for (int i = t; i < 64 * 64; i += 256) {
        int r = i >> 6, c = i & 63;
        wS[r * 65 + c] = W[i];
    }
    for (int i = t; i < 64 * 32; i += 256) {
        int c = i >> 5, j = i & 31;
        xS[c * 33 + j] = x[((size_t)b * C_ + c) * N_ + n0 + j];
    }
    __syncthreads();

    const int o = t & 63, j0 = t >> 6;
#pragma unroll 1
    for (int j = j0; j < 32; j += 4) {
        float acc = 0.f;
#pragma unroll
        for (int c = 0; c < 64; ++c)
            acc = fmaf(wS[o * 65 + c], xS[c * 33 + j], acc);
        bxT[((size_t)b * N_ + n0 + j) * 64 + o] = acc;
    }
}

// ---------------------------------------------------------------------------
// Kernel 3: fused pipeline — one wave per point, zero barriers (R4 structure).
// Changes vs R4: (a) gather reads transposed bxT rows -> coalesced 256 B,
// (b) XCD-aware block swizzle: each XCD owns exactly 2 batches' points so the
// gather working set (~1 MB) stays L2-resident per XCD.
// ---------------------------------------------------------------------------
#define WPB 4
#define NPW 4
#define NBLK (WPB * NPW)   // 16 n per block
#define SLICE 2048         // floats per wave slice (8 KB)

__global__ __launch_bounds__(256, 4)
void fused_kernel(const float* __restrict__ x, const float* __restrict__ glf,
                  const float* __restrict__ appf,
                  const float* __restrict__ dk_W1, const float* __restrict__ dk_b1,
                  const float* __restrict__ dk_g1, const float* __restrict__ dk_be1,
                  const float* __restrict__ dk_W2, const float* __restrict__ dk_b2,
                  const float* __restrict__ act_g, const float* __restrict__ act_b,
                  const float* __restrict__ ff_W1, const float* __restrict__ ff_g1,
                  const float* __restrict__ ff_be1, const float* __restrict__ ff_W2,
                  const float* __restrict__ edge_W, const float* __restrict__ edge_g,
                  const float* __restrict__ edge_be,
                  const float* __restrict__ bxT, const int* __restrict__ idx_ws,
                  float* __restrict__ out) {
    __shared__ float lds[WPB * SLICE];
    const int t = threadIdx.x, wv = t >> 6, l = t & 63;
    float* Wb   = lds + wv * SLICE;
    float* RIF  = Wb;            // [20][64]
    float* SCR  = Wb + 1280;     // appf [20][8] @0 ; h [20][16] @160 ; t [20][32] @0
    float* XCOL = Wb + 1920;     // 64
    int*   IDX  = (int*)(Wb + 1984); // 20

    // XCD-aware swizzle: 2048 blocks = 8 XCD x 256; 2 b per XCD, 128 blocks/b.
    const int raw  = blockIdx.x;
    const int xcd  = raw & 7;
    const int slot = raw >> 3;                 // 0..255
    const int b    = xcd * 2 + (slot >> 7);    // 2 b per xcd
    const int nblk = (slot & 127) * NBLK;
    const int nw0  = nblk + wv * NPW;

    // ---- hoisted per-lane constants (n-invariant) ----
    const int o16 = l >> 2, o32 = l >> 1;
    const int kq5 = (l & 3) * 5, kh10 = (l & 1) * 10;
    const float bdk1h = dk_b1[o16], gdk1h = dk_g1[o16], bedk1h = dk_be1[o16];
    const float bdk2h = dk_b2[o32];
    const float gff1h = ff_g1[o32], beff1h = ff_be1[o32];
    const float gacth = act_g[l],  bacth = act_b[l];
    const float gedgh = edge_g[l], beedgh = edge_be[l];
    const float4 wd1a = *(const float4*)(dk_W1 + o16 * 8);
    const float4 wd1b = *(const float4*)(dk_W1 + o16 * 8 + 4);
    const float4 wd20 = *(const float4*)(dk_W2 + o32 * 16);
    const float4 wd21 = *(const float4*)(dk_W2 + o32 * 16 + 4);
    const float4 wd22 = *(const float4*)(dk_W2 + o32 * 16 + 8);
    const float4 wd23 = *(const float4*)(dk_W2 + o32 * 16 + 12);
    const float* wF1  = ff_W1 + o32 * 64;
    const float* wF2  = ff_W2 + l * 32;
    const float* wEd  = edge_W + l * 128;
    const float* xrow  = x + ((size_t)b * C_ + l) * N_;
    const float* bxb   = bxT + (size_t)b * N_ * 64;

#pragma unroll 1
    for (int i = 0; i < NPW; ++i) {
        const int n = nw0 + i;

        // ---- per-n loads ----
        const float xc = xrow[n];
        XCOL[l] = xc;
        if (l < K_) IDX[l] = idx_ws[((size_t)b * N_ + n) * K_ + l];
        if (l >= 32) {                 // appf: 160 contiguous floats
            const int l2 = l - 32;
            const float4* src = (const float4*)(appf + ((size_t)b * N_ + n) * (K_ * 8));
            *(float4*)(SCR + 4 * l2) = src[l2];
            if (l2 < 8) *(float4*)(SCR + 128 + 4 * l2) = src[32 + l2];
        } else {                       // glf row c2=l -> RIF[k][32+l]
            const float* g = glf + (((size_t)b * 32 + l) * N_ + n) * K_;
#pragma unroll
            for (int kc = 0; kc < 5; ++kc) {
                float4 v = *(const float4*)(g + 4 * kc);
                RIF[(4 * kc + 0) * 64 + 32 + l] = v.x;
                RIF[(4 * kc + 1) * 64 + 32 + l] = v.y;
                RIF[(4 * kc + 2) * 64 + 32 + l] = v.z;
                RIF[(4 * kc + 3) * 64 + 32 + l] = v.w;
            }
        }

        // ---- base_l = edge_W[l, 64:128] . x ----
        float base = 0.f;
#pragma unroll
        for (int c = 0; c < 16; ++c) {
            float4 w4 = *(const float4*)(wEd + 64 + 4 * c);
            float4 x4 = *(const float4*)(XCOL + 4 * c);
            base = fmaf(w4.x, x4.x, base); base = fmaf(w4.y, x4.y, base);
            base = fmaf(w4.z, x4.z, base); base = fmaf(w4.w, x4.w, base);
        }

        // ---- h = relu(bn(dk_W1 @ appf + b1)) : lane -> o=l>>2, k=kq5+q ----
#pragma unroll
        for (int q = 0; q < 5; ++q) {
            const int k = kq5 + q;
            float4 a0 = *(const float4*)(SCR + k * 8);
            float4 a1 = *(const float4*)(SCR + k * 8 + 4);
            float acc = bdk1h;
            acc = fmaf(wd1a.x, a0.x, acc); acc = fmaf(wd1a.y, a0.y, acc);
            acc = fmaf(wd1a.z, a0.z, acc); acc = fmaf(wd1a.w, a0.w, acc);
            acc = fmaf(wd1b.x, a1.x, acc); acc = fmaf(wd1b.y, a1.y, acc);
            acc = fmaf(wd1b.z, a1.z, acc); acc = fmaf(wd1b.w, a1.w, acc);
            float v = acc * gdk1h + bedk1h;
            SCR[160 + k * 16 + o16] = fmaxf(v, 0.f);
        }

        // ---- rif[0:32] = dk_W2 @ h + b2 : lane -> o=l>>1, k=kh10+q ----
#pragma unroll
        for (int q = 0; q < 10; ++q) {
            const int k = kh10 + q;
            const float* hr = SCR + 160 + k * 16;
            float4 h0 = *(const float4*)(hr);
            float4 h1 = *(const float4*)(hr + 4);
            float4 h2 = *(const float4*)(hr + 8);
            float4 h3 = *(const float4*)(hr + 12);
            float acc = bdk2h;
            acc = fmaf(wd20.x, h0.x, acc); acc = fmaf(wd20.y, h0.y, acc);
            acc = fmaf(wd20.z, h0.z, acc); acc = fmaf(wd20.w, h0.w, acc);
            acc = fmaf(wd21.x, h1.x, acc); acc = fmaf(wd21.y, h1.y, acc);
            acc = fmaf(wd21.z, h1.z, acc); acc = fmaf(wd21.w, h1.w, acc);
            acc = fmaf(wd22.x, h2.x, acc); acc = fmaf(wd22.y, h2.y, acc);
            acc = fmaf(wd22.z, h2.z, acc); acc = fmaf(wd22.w, h2.w, acc);
            acc = fmaf(wd23.x, h3.x, acc); acc = fmaf(wd23.y, h3.y, acc);
            acc = fmaf(wd23.z, h3.z, acc); acc = fmaf(wd23.w, h3.w, acc);
            RIF[k * 64 + o32] = acc;
        }

        // ---- t = leaky(bn(ff_W1 @ rif)) : lane -> o=l>>1, k=kh10+q ----
        {
            float acc[10];
#pragma unroll
            for (int q = 0; q < 10; ++q) acc[q] = 0.f;
#pragma unroll
            for (int c = 0; c < 16; ++c) {
                float4 w4 = *(const float4*)(wF1 + 4 * c);
#pragma unroll
                for (int q = 0; q < 10; ++q) {
                    float4 r4 = *(const float4*)(RIF + (kh10 + q) * 64 + 4 * c);
                    acc[q] = fmaf(w4.x, r4.x, acc[q]);
                    acc[q] = fmaf(w4.y, r4.y, acc[q]);
                    acc[q] = fmaf(w4.z, r4.z, acc[q]);
                    acc[q] = fmaf(w4.w, r4.w, acc[q]);
                }
            }
#pragma unroll
            for (int q = 0; q < 10; ++q) {
                float v = acc[q] * gff1h + beff1h;
                v = (v >= 0.f) ? v : NEG_SLOPE * v;
                SCR[(kh10 + q) * 32 + o32] = v;   // t overwrites appf/h (dead)
            }
        }

        // ---- att = sigmoid(ff_W2 @ t); feat = relu(bn(rif*att*gather)) - x ----
        float acc2[20];
#pragma unroll
        for (int k = 0; k < 20; ++k) acc2[k] = 0.f;
#pragma unroll
        for (int c = 0; c < 8; ++c) {
            float4 w4 = *(const float4*)(wF2 + 4 * c);
#pragma unroll
            for (int k = 0; k < 20; ++k) {
                float4 t4 = *(const float4*)(SCR + k * 32 + 4 * c);
                acc2[k] = fmaf(w4.x, t4.x, acc2[k]);
                acc2[k] = fmaf(w4.y, t4.y, acc2[k]);
                acc2[k] = fmaf(w4.z, t4.z, acc2[k]);
                acc2[k] = fmaf(w4.w, t4.w, acc2[k]);
            }
        }
#pragma unroll
        for (int k = 0; k < 20; ++k) {
            float a = 1.f / (1.f + expf(-acc2[k]));
            int kidx = IDX[k];
            float gth = bxb[(size_t)kidx * 64 + l];   // coalesced 256 B row
            float v = RIF[k * 64 + l] * a * gth;
            v = v * gacth + bacth;
            v = fmaxf(v, 0.f) - xc;
            RIF[k * 64 + l] = v;
        }

        // ---- edge conv + bn + leaky + max over k ----
#pragma unroll
        for (int k = 0; k < 20; ++k) acc2[k] = base;
#pragma unroll
        for (int c = 0; c < 16; ++c) {
            float4 w4 = *(const float4*)(wEd + 4 * c);
#pragma unroll
            for (int k = 0; k < 20; ++k) {
                float4 r4 = *(const float4*)(RIF + k * 64 + 4 * c);
                acc2[k] = fmaf(w4.x, r4.x, acc2[k]);
                acc2[k] = fmaf(w4.y, r4.y, acc2[k]);
                acc2[k] = fmaf(w4.z, r4.z, acc2[k]);
                acc2[k] = fmaf(w4.w, r4.w, acc2[k]);
            }
        }
        float mx = -INFINITY;
#pragma unroll
        for (int k = 0; k < 20; ++k) {
            float v = acc2[k] * gedgh + beedgh;
            v = (v >= 0.f) ? v : NEG_SLOPE * v;
            mx = fmaxf(mx, v);
        }
        out[((size_t)b * OUT_ + l) * N_ + n] = mx;
    }
}

// ---------------------------------------------------------------------------
extern "C" void kernel_launch(void* const* d_in, const int* in_sizes, int n_in,
                              void* d_out, int out_size, void* d_ws, size_t ws_size,
                              hipStream_t stream) {
    (void)in_sizes; (void)n_in; (void)out_size; (void)ws_size;
    const float* pos     = (const float*)d_in[0];
    const float* x       = (const float*)d_in[1];
    const float* glf     = (const float*)d_in[2];
    const float* appf    = (const float*)d_in[3];
    const float* basis_W = (const float*)d_in[4];
    const float* dk_W1   = (const float*)d_in[5];
    const float* dk_b1   = (const float*)d_in[6];
    const float* dk_g1   = (const float*)d_in[7];
    const float* dk_be1  = (const float*)d_in[8];
    const float* dk_W2   = (const float*)d_in[9];
    const float* dk_b2   = (const float*)d_in[10];
    const float* act_g   = (const float*)d_in[11];
    const float* act_b   = (const float*)d_in[12];
    const float* ff_W1   = (const float*)d_in[13];
    const float* ff_g1   = (const float*)d_in[14];
    const float* ff_be1  = (const float*)d_in[15];
    const float* ff_W2   = (const float*)d_in[16];
    const float* edge_W  = (const float*)d_in[17];
    const float* edge_g  = (const float*)d_in[18];
    const float* edge_be = (const float*)d_in[19];
    float* out = (float*)d_out;

    int*   idx_ws = (int*)d_ws;
    float* bxT    = (float*)((char*)d_ws + (size_t)B_ * N_ * K_ * sizeof(int));

    hipLaunchKernelGGL(knn_kernel, dim3(B_ * N_ / 4), dim3(256), 0, stream,
                       pos, idx_ws);
    hipLaunchKernelGGL(bx_kernel_t, dim3(N_ / 32, B_), dim3(256), 0, stream,
                       x, basis_W, bxT);
    hipLaunchKernelGGL(fused_kernel, dim3(B_ * (N_ / NBLK)), dim3(256), 0, stream,
                       x, glf, appf, dk_W1, dk_b1, dk_g1, dk_be1, dk_W2, dk_b2,
                       act_g, act_b, ff_W1, ff_g1, ff_be1, ff_W2,
                       edge_W, edge_g, edge_be, bxT, idx_ws, out);
}

// Round 6
// 1549.359 us; speedup vs baseline: 1.8557x; 1.0949x over previous
//
#include <hip/hip_runtime.h>
#include <math.h>

#define B_   16
#define N_   2048
#define K_   20
#define C_   64
#define OUT_ 64
#define NEG_SLOPE 0.2f

// ---------------------------------------------------------------------------
// Kernel 1: KNN — one wave per point (bit-identical math to R4/R5).
// launch_bounds(256,2): allow up to 256 VGPRs so d[32] (64 VGPRs of fp64)
// plus temps never spill to scratch.
// ---------------------------------------------------------------------------
__global__ __launch_bounds__(256, 2)
void knn_kernel(const float* __restrict__ pos, int* __restrict__ idx_out) {
    const int t = threadIdx.x;
    const int wv = t >> 6, l = t & 63;
    const int gid = blockIdx.x * 4 + wv;
    const int b = gid / N_, n = gid % N_;
    const float* pb = pos + (size_t)b * 3 * N_;

    const double qx = (double)pb[n];
    const double qy = (double)pb[N_ + n];
    const double qz = (double)pb[2 * N_ + n];
    const double xxn = qx * qx + qy * qy + qz * qz;

    double d[32];
    const int m0 = l * 32;
#pragma unroll
    for (int j4 = 0; j4 < 8; ++j4) {
        float4 px = *(const float4*)(pb + m0 + 4 * j4);
        float4 py = *(const float4*)(pb + N_ + m0 + 4 * j4);
        float4 pz = *(const float4*)(pb + 2 * N_ + m0 + 4 * j4);
#define DCOMP(JJ, PX, PY, PZ)                                            \
        {   double ddx = (double)(PX), ddy = (double)(PY), ddz = (double)(PZ); \
            double inner = qx * ddx + qy * ddy + qz * ddz;               \
            double xxm   = ddx * ddx + ddy * ddy + ddz * ddz;            \
            d[4 * j4 + JJ] = 2.0 * inner - xxn - xxm; }
        DCOMP(0, px.x, py.x, pz.x)
        DCOMP(1, px.y, py.y, pz.y)
        DCOMP(2, px.z, py.z, pz.z)
        DCOMP(3, px.w, py.w, pz.w)
#undef DCOMP
    }

    unsigned sel = 0u;
    for (int r = 0; r < K_ + 1; ++r) {
        double bk = -INFINITY;
        int bi = 0x7FFFFFFF;
#pragma unroll
        for (int j = 0; j < 32; ++j) {
            bool live = ((sel >> j) & 1u) == 0u;
            if (live && d[j] > bk) { bk = d[j]; bi = m0 + j; }
        }
#pragma unroll
        for (int off = 1; off < 64; off <<= 1) {
            double ok = __shfl_xor(bk, off, 64);
            int    oi = __shfl_xor(bi, off, 64);
            if (ok > bk || (ok == bk && oi < bi)) { bk = ok; bi = oi; }
        }
        if ((bi >> 5) == l) sel |= 1u << (bi & 31);
        if (l == 0 && r > 0) idx_out[(size_t)gid * K_ + (r - 1)] = bi;
    }
}

// ---------------------------------------------------------------------------
// Kernel 2: bxT[b][n][o] = sum_c basis_W[o,c] * x[b,c,n]   (transposed out)
// ---------------------------------------------------------------------------
__global__ __launch_bounds__(256)
void bx_kernel_t(const float* __restrict__ x, const float* __restrict__ W,
                 float* __restrict__ bxT) {
    __shared__ float wS[64 * 65];
    __shared__ float xS[64 * 33];
    const int t = threadIdx.x;
    const int b = blockIdx.y;
    const int n0 = blockIdx.x * 32;

    for (int i = t; i < 64 * 64; i += 256) {
        int r = i >> 6, c = i & 63;
        wS[r * 65 + c] = W[i];
    }
    for (int i = t; i < 64 * 32; i += 256) {
        int c = i >> 5, j = i & 31;
        xS[c * 33 + j] = x[((size_t)b * C_ + c) * N_ + n0 + j];
    }
    __syncthreads();

    const int o = t & 63, j0 = t >> 6;
#pragma unroll 1
    for (int j = j0; j < 32; j += 4) {
        float acc = 0.f;
#pragma unroll
        for (int c = 0; c < 64; ++c)
            acc = fmaf(wS[o * 65 + c], xS[c * 33 + j], acc);
        bxT[((size_t)b * N_ + n0 + j) * 64 + o] = acc;
    }
}

// ---------------------------------------------------------------------------
// Kernel 3: fused pipeline — one wave per point, zero barriers.
// R6 change: __launch_bounds__(256, 2) — the (256,4) bound in R4/R5 capped
// VGPRs at 64 and spilled ~34 KB/point to scratch (the hidden 1.9 GB fetch +
// 1.1 GB write in the counters). R3 evidence: this pipeline wants ~144 VGPRs.
// ---------------------------------------------------------------------------
#define WPB 4
#define NPW 4
#define NBLK (WPB * NPW)   // 16 n per block
#define SLICE 2048         // floats per wave slice (8 KB)

__global__ __launch_bounds__(256, 2)
void fused_kernel(const float* __restrict__ x, const float* __restrict__ glf,
                  const float* __restrict__ appf,
                  const float* __restrict__ dk_W1, const float* __restrict__ dk_b1,
                  const float* __restrict__ dk_g1, const float* __restrict__ dk_be1,
                  const float* __restrict__ dk_W2, const float* __restrict__ dk_b2,
                  const float* __restrict__ act_g, const float* __restrict__ act_b,
                  const float* __restrict__ ff_W1, const float* __restrict__ ff_g1,
                  const float* __restrict__ ff_be1, const float* __restrict__ ff_W2,
                  const float* __restrict__ edge_W, const float* __restrict__ edge_g,
                  const float* __restrict__ edge_be,
                  const float* __restrict__ bxT, const int* __restrict__ idx_ws,
                  float* __restrict__ out) {
    __shared__ float lds[WPB * SLICE];
    const int t = threadIdx.x, wv = t >> 6, l = t & 63;
    float* Wb   = lds + wv * SLICE;
    float* RIF  = Wb;            // [20][64]
    float* SCR  = Wb + 1280;     // appf [20][8] @0 ; h [20][16] @160 ; t [20][32] @0
    float* XCOL = Wb + 1920;     // 64
    int*   IDX  = (int*)(Wb + 1984); // 20

    // XCD-aware swizzle: 2048 blocks = 8 XCD x 256; 2 b per XCD, 128 blocks/b.
    const int raw  = blockIdx.x;
    const int xcd  = raw & 7;
    const int slot = raw >> 3;                 // 0..255
    const int b    = xcd * 2 + (slot >> 7);    // 2 b per xcd
    const int nblk = (slot & 127) * NBLK;
    const int nw0  = nblk + wv * NPW;

    // ---- hoisted per-lane constants (n-invariant) ----
    const int o16 = l >> 2, o32 = l >> 1;
    const int kq5 = (l & 3) * 5, kh10 = (l & 1) * 10;
    const float bdk1h = dk_b1[o16], gdk1h = dk_g1[o16], bedk1h = dk_be1[o16];
    const float bdk2h = dk_b2[o32];
    const float gff1h = ff_g1[o32], beff1h = ff_be1[o32];
    const float gacth = act_g[l],  bacth = act_b[l];
    const float gedgh = edge_g[l], beedgh = edge_be[l];
    const float4 wd1a = *(const float4*)(dk_W1 + o16 * 8);
    const float4 wd1b = *(const float4*)(dk_W1 + o16 * 8 + 4);
    const float4 wd20 = *(const float4*)(dk_W2 + o32 * 16);
    const float4 wd21 = *(const float4*)(dk_W2 + o32 * 16 + 4);
    const float4 wd22 = *(const float4*)(dk_W2 + o32 * 16 + 8);
    const float4 wd23 = *(const float4*)(dk_W2 + o32 * 16 + 12);
    const float* wF1  = ff_W1 + o32 * 64;
    const float* wF2  = ff_W2 + l * 32;
    const float* wEd  = edge_W + l * 128;
    const float* xrow  = x + ((size_t)b * C_ + l) * N_;
    const float* bxb   = bxT + (size_t)b * N_ * 64;

#pragma unroll 1
    for (int i = 0; i < NPW; ++i) {
        const int n = nw0 + i;

        // ---- per-n loads ----
        const float xc = xrow[n];
        XCOL[l] = xc;
        if (l < K_) IDX[l] = idx_ws[((size_t)b * N_ + n) * K_ + l];
        if (l >= 32) {                 // appf: 160 contiguous floats
            const int l2 = l - 32;
            const float4* src = (const float4*)(appf + ((size_t)b * N_ + n) * (K_ * 8));
            *(float4*)(SCR + 4 * l2) = src[l2];
            if (l2 < 8) *(float4*)(SCR + 128 + 4 * l2) = src[32 + l2];
        } else {                       // glf row c2=l -> RIF[k][32+l]
            const float* g = glf + (((size_t)b * 32 + l) * N_ + n) * K_;
#pragma unroll
            for (int kc = 0; kc < 5; ++kc) {
                float4 v = *(const float4*)(g + 4 * kc);
                RIF[(4 * kc + 0) * 64 + 32 + l] = v.x;
                RIF[(4 * kc + 1) * 64 + 32 + l] = v.y;
                RIF[(4 * kc + 2) * 64 + 32 + l] = v.z;
                RIF[(4 * kc + 3) * 64 + 32 + l] = v.w;
            }
        }

        // ---- base_l = edge_W[l, 64:128] . x ----
        float base = 0.f;
#pragma unroll
        for (int c = 0; c < 16; ++c) {
            float4 w4 = *(const float4*)(wEd + 64 + 4 * c);
            float4 x4 = *(const float4*)(XCOL + 4 * c);
            base = fmaf(w4.x, x4.x, base); base = fmaf(w4.y, x4.y, base);
            base = fmaf(w4.z, x4.z, base); base = fmaf(w4.w, x4.w, base);
        }

        // ---- h = relu(bn(dk_W1 @ appf + b1)) : lane -> o=l>>2, k=kq5+q ----
#pragma unroll
        for (int q = 0; q < 5; ++q) {
            const int k = kq5 + q;
            float4 a0 = *(const float4*)(SCR + k * 8);
            float4 a1 = *(const float4*)(SCR + k * 8 + 4);
            float acc = bdk1h;
            acc = fmaf(wd1a.x, a0.x, acc); acc = fmaf(wd1a.y, a0.y, acc);
            acc = fmaf(wd1a.z, a0.z, acc); acc = fmaf(wd1a.w, a0.w, acc);
            acc = fmaf(wd1b.x, a1.x, acc); acc = fmaf(wd1b.y, a1.y, acc);
            acc = fmaf(wd1b.z, a1.z, acc); acc = fmaf(wd1b.w, a1.w, acc);
            float v = acc * gdk1h + bedk1h;
            SCR[160 + k * 16 + o16] = fmaxf(v, 0.f);
        }

        // ---- rif[0:32] = dk_W2 @ h + b2 : lane -> o=l>>1, k=kh10+q ----
#pragma unroll
        for (int q = 0; q < 10; ++q) {
            const int k = kh10 + q;
            const float* hr = SCR + 160 + k * 16;
            float4 h0 = *(const float4*)(hr);
            float4 h1 = *(const float4*)(hr + 4);
            float4 h2 = *(const float4*)(hr + 8);
            float4 h3 = *(const float4*)(hr + 12);
            float acc = bdk2h;
            acc = fmaf(wd20.x, h0.x, acc); acc = fmaf(wd20.y, h0.y, acc);
            acc = fmaf(wd20.z, h0.z, acc); acc = fmaf(wd20.w, h0.w, acc);
            acc = fmaf(wd21.x, h1.x, acc); acc = fmaf(wd21.y, h1.y, acc);
            acc = fmaf(wd21.z, h1.z, acc); acc = fmaf(wd21.w, h1.w, acc);
            acc = fmaf(wd22.x, h2.x, acc); acc = fmaf(wd22.y, h2.y, acc);
            acc = fmaf(wd22.z, h2.z, acc); acc = fmaf(wd22.w, h2.w, acc);
            acc = fmaf(wd23.x, h3.x, acc); acc = fmaf(wd23.y, h3.y, acc);
            acc = fmaf(wd23.z, h3.z, acc); acc = fmaf(wd23.w, h3.w, acc);
            RIF[k * 64 + o32] = acc;
        }

        // ---- t = leaky(bn(ff_W1 @ rif)) : lane -> o=l>>1, k=kh10+q ----
        {
            float acc[10];
#pragma unroll
            for (int q = 0; q < 10; ++q) acc[q] = 0.f;
#pragma unroll
            for (int c = 0; c < 16; ++c) {
                float4 w4 = *(const float4*)(wF1 + 4 * c);
#pragma unroll
                for (int q = 0; q < 10; ++q) {
                    float4 r4 = *(const float4*)(RIF + (kh10 + q) * 64 + 4 * c);
                    acc[q] = fmaf(w4.x, r4.x, acc[q]);
                    acc[q] = fmaf(w4.y, r4.y, acc[q]);
                    acc[q] = fmaf(w4.z, r4.z, acc[q]);
                    acc[q] = fmaf(w4.w, r4.w, acc[q]);
                }
            }
#pragma unroll
            for (int q = 0; q < 10; ++q) {
                float v = acc[q] * gff1h + beff1h;
                v = (v >= 0.f) ? v : NEG_SLOPE * v;
                SCR[(kh10 + q) * 32 + o32] = v;   // t overwrites appf/h (dead)
            }
        }

        // ---- att = sigmoid(ff_W2 @ t); feat = relu(bn(rif*att*gather)) - x ----
        float acc2[20];
#pragma unroll
        for (int k = 0; k < 20; ++k) acc2[k] = 0.f;
#pragma unroll
        for (int c = 0; c < 8; ++c) {
            float4 w4 = *(const float4*)(wF2 + 4 * c);
#pragma unroll
            for (int k = 0; k < 20; ++k) {
                float4 t4 = *(const float4*)(SCR + k * 32 + 4 * c);
                acc2[k] = fmaf(w4.x, t4.x, acc2[k]);
                acc2[k] = fmaf(w4.y, t4.y, acc2[k]);
                acc2[k] = fmaf(w4.z, t4.z, acc2[k]);
                acc2[k] = fmaf(w4.w, t4.w, acc2[k]);
            }
        }
#pragma unroll
        for (int k = 0; k < 20; ++k) {
            float a = 1.f / (1.f + expf(-acc2[k]));
            int kidx = IDX[k];
            float gth = bxb[(size_t)kidx * 64 + l];   // coalesced 256 B row
            float v = RIF[k * 64 + l] * a * gth;
            v = v * gacth + bacth;
            v = fmaxf(v, 0.f) - xc;
            RIF[k * 64 + l] = v;
        }

        // ---- edge conv + bn + leaky + max over k ----
#pragma unroll
        for (int k = 0; k < 20; ++k) acc2[k] = base;
#pragma unroll
        for (int c = 0; c < 16; ++c) {
            float4 w4 = *(const float4*)(wEd + 4 * c);
#pragma unroll
            for (int k = 0; k < 20; ++k) {
                float4 r4 = *(const float4*)(RIF + k * 64 + 4 * c);
                acc2[k] = fmaf(w4.x, r4.x, acc2[k]);
                acc2[k] = fmaf(w4.y, r4.y, acc2[k]);
                acc2[k] = fmaf(w4.z, r4.z, acc2[k]);
                acc2[k] = fmaf(w4.w, r4.w, acc2[k]);
            }
        }
        float mx = -INFINITY;
#pragma unroll
        for (int k = 0; k < 20; ++k) {
            float v = acc2[k] * gedgh + beedgh;
            v = (v >= 0.f) ? v : NEG_SLOPE * v;
            mx = fmaxf(mx, v);
        }
        out[((size_t)b * OUT_ + l) * N_ + n] = mx;
    }
}

// ---------------------------------------------------------------------------
extern "C" void kernel_launch(void* const* d_in, const int* in_sizes, int n_in,
                              void* d_out, int out_size, void* d_ws, size_t ws_size,
                              hipStream_t stream) {
    (void)in_sizes; (void)n_in; (void)out_size; (void)ws_size;
    const float* pos     = (const float*)d_in[0];
    const float* x       = (const float*)d_in[1];
    const float* glf     = (const float*)d_in[2];
    const float* appf    = (const float*)d_in[3];
    const float* basis_W = (const float*)d_in[4];
    const float* dk_W1   = (const float*)d_in[5];
    const float* dk_b1   = (const float*)d_in[6];
    const float* dk_g1   = (const float*)d_in[7];
    const float* dk_be1  = (const float*)d_in[8];
    const float* dk_W2   = (const float*)d_in[9];
    const float* dk_b2   = (const float*)d_in[10];
    const float* act_g   = (const float*)d_in[11];
    const float* act_b   = (const float*)d_in[12];
    const float* ff_W1   = (const float*)d_in[13];
    const float* ff_g1   = (const float*)d_in[14];
    const float* ff_be1  = (const float*)d_in[15];
    const float* ff_W2   = (const float*)d_in[16];
    const float* edge_W  = (const float*)d_in[17];
    const float* edge_g  = (const float*)d_in[18];
    const float* edge_be = (const float*)d_in[19];
    float* out = (float*)d_out;

    int*   idx_ws = (int*)d_ws;
    float* bxT    = (float*)((char*)d_ws + (size_t)B_ * N_ * K_ * sizeof(int));

    hipLaunchKernelGGL(knn_kernel, dim3(B_ * N_ / 4), dim3(256), 0, stream,
                       pos, idx_ws);
    hipLaunchKernelGGL(bx_kernel_t, dim3(N_ / 32, B_), dim3(256), 0, stream,
                       x, basis_W, bxT);
    hipLaunchKernelGGL(fused_kernel, dim3(B_ * (N_ / NBLK)), dim3(256), 0, stream,
                       x, glf, appf, dk_W1, dk_b1, dk_g1, dk_be1, dk_W2, dk_b2,
                       act_g, act_b, ff_W1, ff_g1, ff_be1, ff_W2,
                       edge_W, edge_g, edge_be, bxT, idx_ws, out);
}